// Round 2
// baseline (473.956 us; speedup 1.0000x reference)
//
#include <hip/hip_runtime.h>
#include <math.h>

#define N_NODES 8192
#define F_DIM   2048
#define E_EDGES 262144
#define H1      32
#define H2      16
#define ALPHA_C 0.9f

typedef float f4v __attribute__((ext_vector_type(4)));

// ---------------------------------------------------------------------------
// K1: in-degree histogram over dst
__global__ void k_degree(const int* __restrict__ dst, int* __restrict__ deg) {
    int e = blockIdx.x * 256 + threadIdx.x;
    if (e < E_EDGES) atomicAdd(&deg[dst[e]], 1);
}

// ---------------------------------------------------------------------------
// K2: exclusive prefix scan of deg -> rowptr, cursor; norm = rsqrt(max(deg,1))
// shuffle-based scan: 2 barriers instead of 20 (single-block critical path)
__global__ void k_scan(const int* __restrict__ deg, int* __restrict__ rowptr,
                       int* __restrict__ cursor, float* __restrict__ norm) {
    __shared__ int wsum[16];
    int t = threadIdx.x;          // 0..1023
    int base = t * 8;
    int local[8];
    int s = 0;
#pragma unroll
    for (int i = 0; i < 8; i++) { local[i] = s; s += deg[base + i]; }
    int lane = t & 63, wv = t >> 6;
    int incl = s;
#pragma unroll
    for (int off = 1; off < 64; off <<= 1) {
        int u = __shfl_up(incl, off);
        if (lane >= off) incl += u;
    }
    if (lane == 63) wsum[wv] = incl;
    __syncthreads();
    if (t < 16) {
        int x = wsum[t];
#pragma unroll
        for (int off = 1; off < 16; off <<= 1) {
            int u = __shfl_up(x, off);
            if (t >= off) x += u;
        }
        wsum[t] = x;   // inclusive scan of the 16 wave sums
    }
    __syncthreads();
    int waveoff = (wv == 0) ? 0 : wsum[wv - 1];
    int excl = waveoff + incl - s;   // exclusive offset for this thread's 8 elems
#pragma unroll
    for (int i = 0; i < 8; i++) {
        int r = excl + local[i];
        rowptr[base + i] = r;
        cursor[base + i] = r;
        int d = ((i == 7) ? s : local[i + 1]) - local[i];
        norm[base + i] = rsqrtf((float)(d > 0 ? d : 1));
    }
    if (t == 1023) rowptr[N_NODES] = waveoff + incl;
}

// ---------------------------------------------------------------------------
// K3: scatter edges into CSR (counting sort; order within segment irrelevant)
__global__ void k_scatter(const int* __restrict__ src, const int* __restrict__ dst,
                          int* __restrict__ cursor, int* __restrict__ csr_src) {
    int e = blockIdx.x * 256 + threadIdx.x;
    if (e < E_EDGES) {
        int d = dst[e];
        int p = atomicAdd(&cursor[d], 1);
        csr_src[p] = src[e];
    }
}

// ---------------------------------------------------------------------------
// K4: xw = feat @ W0   [8192,2048]@[2048,32], fp32 vector-ALU tiled GEMM.
// BM=256, BN=32, BK=32, 256 threads, TM=8 (rows rt+32m), TN=4 (cols ct+8j).
// TM=8 cuts LDS-read bytes/FMA 2.0->1.5 (was the bound at ~20us).
// split-K = 16 (grid.y, 128 K each) -> 512 blocks, 2-3/CU (LDS 41KB).
__global__ __launch_bounds__(256) void k_gemm_xw(const float* __restrict__ feat,
                                                 const float* __restrict__ W0,
                                                 float* __restrict__ xw) {
    __shared__ float As[256][36];
    __shared__ float Bt[32][36];
    const int r0 = blockIdx.x * 256;
    const int kbase = blockIdx.y * 128;
    const int t = threadIdx.x;
    const int ct = t & 7;    // 8 col-threads  (cols ct + 8j)
    const int rt = t >> 3;   // 32 row-threads (rows rt + 32m)
    float acc[8][4] = {};
    for (int kb = 0; kb < 128; kb += 32) {
        const int koff = kbase + kb;
        __syncthreads();
        // stage A tile: 256 rows x 32 k = 2048 float4, 8 per thread (coalesced)
#pragma unroll
        for (int p = 0; p < 8; p++) {
            int f = t + p * 256;
            int row = f >> 3, q = f & 7;
            float4 v = *(const float4*)&feat[(size_t)(r0 + row) * F_DIM + koff + q * 4];
            *(float4*)&As[row][q * 4] = v;
        }
        // stage B tile transposed: 32 k x 32 cols, 1 float4 per thread
        {
            int kk = t >> 3, q = t & 7;
            float4 v = *(const float4*)&W0[(size_t)(koff + kk) * H1 + q * 4];
            Bt[q * 4 + 0][kk] = v.x; Bt[q * 4 + 1][kk] = v.y;
            Bt[q * 4 + 2][kk] = v.z; Bt[q * 4 + 3][kk] = v.w;
        }
        __syncthreads();
#pragma unroll
        for (int k4 = 0; k4 < 8; k4++) {
            float4 a[8], b[4];
#pragma unroll
            for (int j = 0; j < 4; j++) b[j] = *(const float4*)&Bt[ct + 8 * j][k4 * 4];
#pragma unroll
            for (int m = 0; m < 8; m++) a[m] = *(const float4*)&As[rt + 32 * m][k4 * 4];
#pragma unroll
            for (int m = 0; m < 8; m++)
#pragma unroll
                for (int j = 0; j < 4; j++)
                    acc[m][j] += a[m].x * b[j].x + a[m].y * b[j].y +
                                 a[m].z * b[j].z + a[m].w * b[j].w;
        }
    }
#pragma unroll
    for (int m = 0; m < 8; m++)
#pragma unroll
        for (int j = 0; j < 4; j++)
            atomicAdd(&xw[(size_t)(r0 + rt + 32 * m) * H1 + ct + 8 * j], acc[m][j]);
}

// ---------------------------------------------------------------------------
// K5 (fused): first graph conv + per-node small math.
// One wave per node: 2 edges/iter (half0 even slot, half1 odd slot), scalarized
// csr loads (readfirstlane -> scalar). After reduce all lanes hold h row.
// Then: h write, dd/ds shuffle-reduce, hm via wave-private LDS row.
// NOTE no __syncthreads(): sh row is wave-private; same-wave DS write->read is
// in-order, and compiler cannot disambiguate the aliasing LDS accesses.
__global__ __launch_bounds__(256) void k_agg1f(const int* __restrict__ rowptr,
                                               const int* __restrict__ csr_src,
                                               const float* __restrict__ xw,
                                               const float* __restrict__ norm,
                                               const float* __restrict__ Wm,
                                               const float* __restrict__ gw,
                                               float* __restrict__ h,
                                               float* __restrict__ hm,
                                               float* __restrict__ dd,
                                               float* __restrict__ ds) {
    __shared__ float sh[4][H1];  // wave-private row, no block barrier needed
    int wid = (blockIdx.x * blockDim.x + threadIdx.x) >> 6;  // node (wave-uniform)
    int w = (threadIdx.x >> 6) & 3;
    int lane = threadIdx.x & 63;
    int col = lane & 31, half = lane >> 5;
    int beg = __builtin_amdgcn_readfirstlane(rowptr[wid]);
    int end = __builtin_amdgcn_readfirstlane(rowptr[wid + 1]);
    float acc = 0.0f;
    int p = beg;
    for (; p + 1 < end; p += 2) {
        int s0 = __builtin_amdgcn_readfirstlane(csr_src[p]);
        int s1 = __builtin_amdgcn_readfirstlane(csr_src[p + 1]);
        float n0 = norm[s0], n1 = norm[s1];
        int s = half ? s1 : s0;
        float nn = half ? n1 : n0;
        acc += nn * xw[(size_t)s * H1 + col];
    }
    if (p < end) {
        int s0 = __builtin_amdgcn_readfirstlane(csr_src[p]);
        if (!half) acc += norm[s0] * xw[(size_t)s0 * H1 + col];
    }
    acc += __shfl_xor(acc, 32);           // both halves now hold col total
    float norm_n = norm[wid];
    float hv = fmaxf(norm_n * acc, 0.0f);
    if (!half) {
        h[(size_t)wid * H1 + col] = hv;
        sh[w][col] = hv;
    }
    // gate dots: half1 contributes 0 (values duplicated across halves)
    float c0 = half ? 0.0f : hv * gw[col];
    float c1 = half ? 0.0f : hv * gw[H1 + col];
#pragma unroll
    for (int off = 1; off < 64; off <<= 1) {
        c0 += __shfl_xor(c0, off);
        c1 += __shfl_xor(c1, off);
    }
    if (lane == 0) { dd[wid] = c0; ds[wid] = c1; }
    // hm[k] = norm_n * sum_c h[c]*Wm[c][k] on lanes 32..47
    if (half && col < 16) {
        int k = lane & 15;
        float s2 = 0.0f;
#pragma unroll
        for (int c = 0; c < H1; c++) s2 += sh[w][c] * Wm[c * H2 + k];
        hm[(size_t)wid * H2 + k] = norm_n * s2;
    }
}

// ---------------------------------------------------------------------------
// K6 (fused): edge-gated aggregation + mean + logstd + reparameterize.
// 2 edges/iter; scalarized uniform loads; fast tanh via exp; lanes 32..47
// accumulate mean over even slots, 48..63 over odd; no block barrier
// (wave-private LDS row -> no cross-wave wait on longest edge list).
__global__ __launch_bounds__(256) void k_agg2z(const int* __restrict__ rowptr,
                                               const int* __restrict__ csr_src,
                                               const float* __restrict__ h,
                                               const float* __restrict__ hm,
                                               const float* __restrict__ dd,
                                               const float* __restrict__ ds,
                                               const float* __restrict__ norm,
                                               const float* __restrict__ gb,
                                               const float* __restrict__ t2,
                                               const float* __restrict__ noise,
                                               float* __restrict__ z) {
    __shared__ float sh[4][H1];
    int wid = (blockIdx.x * blockDim.x + threadIdx.x) >> 6;  // node id
    int w = (threadIdx.x >> 6) & 3;
    int lane = threadIdx.x & 63;
    int col = lane & 31;
    int k = lane & 15;
    int beg = __builtin_amdgcn_readfirstlane(rowptr[wid]);
    int end = __builtin_amdgcn_readfirstlane(rowptr[wid + 1]);
    float dd_n = dd[wid];
    float norm_n = norm[wid];
    float gb0 = gb[0];
    bool isZ = lane < 32;
    float accz = 0.0f, accm = 0.0f;
    int p = beg;
    for (; p + 1 < end; p += 2) {
        int s0 = __builtin_amdgcn_readfirstlane(csr_src[p]);
        int s1 = __builtin_amdgcn_readfirstlane(csr_src[p + 1]);
        float x0 = fminf(dd_n + ds[s0] + gb0, 15.0f);
        float x1 = fminf(dd_n + ds[s1] + gb0, 15.0f);
        float e0 = __expf(2.0f * x0), e1 = __expf(2.0f * x1);
        float cf0 = __fdividef(e0 - 1.0f, e0 + 1.0f) * norm[s0];
        float cf1 = __fdividef(e1 - 1.0f, e1 + 1.0f) * norm[s1];
        if (isZ) {
            accz += cf0 * h[(size_t)s0 * H1 + col] + cf1 * h[(size_t)s1 * H1 + col];
        } else {
            int sm = (lane < 48) ? s0 : s1;
            accm += hm[(size_t)sm * H2 + k];
        }
    }
    if (p < end) {
        int s0 = __builtin_amdgcn_readfirstlane(csr_src[p]);
        float x0 = fminf(dd_n + ds[s0] + gb0, 15.0f);
        float e0 = __expf(2.0f * x0);
        float cf0 = __fdividef(e0 - 1.0f, e0 + 1.0f) * norm[s0];
        if (isZ) accz += cf0 * h[(size_t)s0 * H1 + col];
        else if (lane < 48) accm += hm[(size_t)s0 * H2 + k];
    }
    // t[c] = z_auto[c] + alpha*h[n][c]  (norm_n*alpha folded out of the sum)
    if (isZ) sh[w][col] = accz * (norm_n * ALPHA_C) + ALPHA_C * h[(size_t)wid * H1 + col];
    accm += __shfl_xor(accm, 16);        // even+odd mean partials
    if (!isZ && lane < 48) {
        float ls = 0.0f;
#pragma unroll
        for (int c = 0; c < H1; c++) ls += sh[w][c] * t2[c * H2 + k];
        size_t zi = (size_t)wid * H2 + k;
        z[zi] = noise[zi] * __expf(ls) + norm_n * accm;
    }
}

// ---------------------------------------------------------------------------
// K7: out = sigmoid(z @ z^T), 128x128 tile per block, 8x8 per thread.
__global__ __launch_bounds__(256) void k_outer(const float* __restrict__ z,
                                               float* __restrict__ out) {
    __shared__ float Zr[H2][128];
    __shared__ float Zc[H2][128];
    const int bx = blockIdx.x, by = blockIdx.y;
    const int t = threadIdx.x;
#pragma unroll
    for (int p = 0; p < 2; p++) {
        int fi = t + p * 256;
        int row = fi >> 2, q = fi & 3;
        float4 v = *(const float4*)&z[(size_t)(by * 128 + row) * H2 + q * 4];
        Zr[q * 4 + 0][row] = v.x; Zr[q * 4 + 1][row] = v.y;
        Zr[q * 4 + 2][row] = v.z; Zr[q * 4 + 3][row] = v.w;
        float4 w = *(const float4*)&z[(size_t)(bx * 128 + row) * H2 + q * 4];
        Zc[q * 4 + 0][row] = w.x; Zc[q * 4 + 1][row] = w.y;
        Zc[q * 4 + 2][row] = w.z; Zc[q * 4 + 3][row] = w.w;
    }
    __syncthreads();
    const int tx = t & 15, ty = t >> 4;
    float acc[8][8] = {};
#pragma unroll
    for (int k = 0; k < H2; k++) {
        float a[8], b[8];
        *(float4*)&a[0] = *(const float4*)&Zr[k][ty * 4];
        *(float4*)&a[4] = *(const float4*)&Zr[k][64 + ty * 4];
        *(float4*)&b[0] = *(const float4*)&Zc[k][tx * 4];
        *(float4*)&b[4] = *(const float4*)&Zc[k][64 + tx * 4];
#pragma unroll
        for (int i = 0; i < 8; i++)
#pragma unroll
            for (int j = 0; j < 8; j++) acc[i][j] += a[i] * b[j];
    }
#pragma unroll
    for (int i = 0; i < 8; i++) {
        size_t row = (size_t)by * 128 + ((i < 4) ? (ty * 4 + i) : (64 + ty * 4 + i - 4));
        f4v o0, o1;
        o0.x = 1.0f / (1.0f + __expf(-acc[i][0]));
        o0.y = 1.0f / (1.0f + __expf(-acc[i][1]));
        o0.z = 1.0f / (1.0f + __expf(-acc[i][2]));
        o0.w = 1.0f / (1.0f + __expf(-acc[i][3]));
        o1.x = 1.0f / (1.0f + __expf(-acc[i][4]));
        o1.y = 1.0f / (1.0f + __expf(-acc[i][5]));
        o1.z = 1.0f / (1.0f + __expf(-acc[i][6]));
        o1.w = 1.0f / (1.0f + __expf(-acc[i][7]));
        __builtin_nontemporal_store(o0, (f4v*)&out[row * N_NODES + bx * 128 + tx * 4]);
        __builtin_nontemporal_store(o1, (f4v*)&out[row * N_NODES + bx * 128 + 64 + tx * 4]);
    }
}

// ---------------------------------------------------------------------------
extern "C" void kernel_launch(void* const* d_in, const int* in_sizes, int n_in,
                              void* d_out, int out_size, void* d_ws, size_t ws_size,
                              hipStream_t stream) {
    const float* feat  = (const float*)d_in[0];
    const float* W0    = (const float*)d_in[1];
    const float* Wm    = (const float*)d_in[2];
    const float* gw    = (const float*)d_in[3];
    const float* gb    = (const float*)d_in[4];
    const float* t2    = (const float*)d_in[5];
    const float* noise = (const float*)d_in[6];
    const int*   src   = (const int*)d_in[7];
    const int*   dst   = (const int*)d_in[8];
    float* out = (float*)d_out;

    char* w = (char*)d_ws;
    size_t off = 0;
    auto alloc = [&](size_t bytes) {
        void* p = w + off;
        off = (off + bytes + 255) & ~(size_t)255;
        return p;
    };
    // deg and xw first + contiguous -> single zeroing memset
    int*   deg     = (int*)alloc(N_NODES * 4);
    float* xw      = (float*)alloc((size_t)N_NODES * H1 * 4);
    size_t zero_bytes = off;
    int*   rowptr  = (int*)alloc((N_NODES + 1) * 4);
    int*   cursor  = (int*)alloc(N_NODES * 4);
    int*   csr_src = (int*)alloc(E_EDGES * 4);
    float* norm    = (float*)alloc(N_NODES * 4);
    float* h       = (float*)alloc((size_t)N_NODES * H1 * 4);
    float* hm      = (float*)alloc((size_t)N_NODES * H2 * 4);
    float* dd      = (float*)alloc(N_NODES * 4);
    float* ds      = (float*)alloc(N_NODES * 4);
    float* z       = (float*)alloc((size_t)N_NODES * H2 * 4);

    (void)hipMemsetAsync(deg, 0, zero_bytes, stream);

    k_degree<<<E_EDGES / 256, 256, 0, stream>>>(dst, deg);
    k_scan<<<1, 1024, 0, stream>>>(deg, rowptr, cursor, norm);
    k_scatter<<<E_EDGES / 256, 256, 0, stream>>>(src, dst, cursor, csr_src);
    k_gemm_xw<<<dim3(N_NODES / 256, 16), 256, 0, stream>>>(feat, W0, xw);
    k_agg1f<<<N_NODES / 4, 256, 0, stream>>>(rowptr, csr_src, xw, norm, Wm, gw,
                                             h, hm, dd, ds);
    k_agg2z<<<N_NODES / 4, 256, 0, stream>>>(rowptr, csr_src, h, hm, dd, ds, norm,
                                             gb, t2, noise, z);
    k_outer<<<dim3(N_NODES / 128, N_NODES / 128), 256, 0, stream>>>(z, out);
}

// Round 3
// 443.003 us; speedup vs baseline: 1.0699x; 1.0699x over previous
//
#include <hip/hip_runtime.h>
#include <math.h>

#define N_NODES 8192
#define F_DIM   2048
#define E_EDGES 262144
#define H1      32
#define H2      16
#define ALPHA_C 0.9f

typedef float f4v __attribute__((ext_vector_type(4)));

// ---------------------------------------------------------------------------
// K1 (fused): blocks [0,1024) = GEMM xw = feat @ W0; blocks [1024,2048) =
// in-degree histogram. The two are independent; fusing them overlaps the
// ~5us of degree atomics under the ~12us GEMM instead of serializing.
// GEMM path is the round-0 proven config: BM=128, BN=32, BK=32, 256 thr,
// TM=4, TN=4, split-K=16 (1024 gemm blocks -> 4 blocks/CU, 16 waves/CU).
__global__ __launch_bounds__(256) void k_gemm_deg(const float* __restrict__ feat,
                                                  const float* __restrict__ W0,
                                                  float* __restrict__ xw,
                                                  const int* __restrict__ dst,
                                                  int* __restrict__ deg) {
    __shared__ float As[128][36];
    __shared__ float Bt[32][36];
    const int b = blockIdx.x;
    if (b >= 1024) {
        // ---- degree histogram path (verbatim round-0 k_degree) ----
        int e = (b - 1024) * 256 + threadIdx.x;
        if (e < E_EDGES) atomicAdd(&deg[dst[e]], 1);
        return;
    }
    // ---- GEMM path (verbatim round-0 k_gemm_xw, grid flattened) ----
    const int r0 = (b >> 4) * 128;        // 64 row-blocks
    const int kbase = (b & 15) * 128;     // 16 K-slices
    const int t = threadIdx.x;
    const int ct = t & 7;    // 8 col-threads  (cols ct + 8j)
    const int rt = t >> 3;   // 32 row-threads (rows rt + 32m)
    float acc[4][4] = {};
    for (int kb = 0; kb < 128; kb += 32) {
        const int koff = kbase + kb;
        __syncthreads();
        // stage A tile: 128 rows x 32 k = 1024 float4, 4 per thread (coalesced)
#pragma unroll
        for (int p = 0; p < 4; p++) {
            int f = t + p * 256;
            int row = f >> 3, q = f & 7;
            float4 v = *(const float4*)&feat[(size_t)(r0 + row) * F_DIM + koff + q * 4];
            *(float4*)&As[row][q * 4] = v;
        }
        // stage B tile transposed: 32 k x 32 cols, 1 float4 per thread
        {
            int k = t >> 3, q = t & 7;
            float4 v = *(const float4*)&W0[(size_t)(koff + k) * H1 + q * 4];
            Bt[q * 4 + 0][k] = v.x; Bt[q * 4 + 1][k] = v.y;
            Bt[q * 4 + 2][k] = v.z; Bt[q * 4 + 3][k] = v.w;
        }
        __syncthreads();
#pragma unroll
        for (int k4 = 0; k4 < 8; k4++) {
            float4 a[4], bb[4];
#pragma unroll
            for (int m = 0; m < 4; m++) a[m] = *(const float4*)&As[rt + 32 * m][k4 * 4];
#pragma unroll
            for (int j = 0; j < 4; j++) bb[j] = *(const float4*)&Bt[ct + 8 * j][k4 * 4];
#pragma unroll
            for (int m = 0; m < 4; m++)
#pragma unroll
                for (int j = 0; j < 4; j++)
                    acc[m][j] += a[m].x * bb[j].x + a[m].y * bb[j].y +
                                 a[m].z * bb[j].z + a[m].w * bb[j].w;
        }
    }
#pragma unroll
    for (int m = 0; m < 4; m++)
#pragma unroll
        for (int j = 0; j < 4; j++)
            atomicAdd(&xw[(size_t)(r0 + rt + 32 * m) * H1 + ct + 8 * j], acc[m][j]);
}

// ---------------------------------------------------------------------------
// K2: exclusive prefix scan of deg -> rowptr, cursor; norm = rsqrt(max(deg,1))
// shuffle-based scan: 2 barriers instead of 20 (single-block critical path);
// hardware-verified correct in round 2.
__global__ void k_scan(const int* __restrict__ deg, int* __restrict__ rowptr,
                       int* __restrict__ cursor, float* __restrict__ norm) {
    __shared__ int wsum[16];
    int t = threadIdx.x;          // 0..1023
    int base = t * 8;
    int local[8];
    int s = 0;
#pragma unroll
    for (int i = 0; i < 8; i++) { local[i] = s; s += deg[base + i]; }
    int lane = t & 63, wv = t >> 6;
    int incl = s;
#pragma unroll
    for (int off = 1; off < 64; off <<= 1) {
        int u = __shfl_up(incl, off);
        if (lane >= off) incl += u;
    }
    if (lane == 63) wsum[wv] = incl;
    __syncthreads();
    if (t < 16) {
        int x = wsum[t];
#pragma unroll
        for (int off = 1; off < 16; off <<= 1) {
            int u = __shfl_up(x, off);
            if (t >= off) x += u;
        }
        wsum[t] = x;   // inclusive scan of the 16 wave sums
    }
    __syncthreads();
    int waveoff = (wv == 0) ? 0 : wsum[wv - 1];
    int excl = waveoff + incl - s;   // exclusive offset for this thread's 8 elems
#pragma unroll
    for (int i = 0; i < 8; i++) {
        int r = excl + local[i];
        rowptr[base + i] = r;
        cursor[base + i] = r;
        int d = ((i == 7) ? s : local[i + 1]) - local[i];
        norm[base + i] = rsqrtf((float)(d > 0 ? d : 1));
    }
    if (t == 1023) rowptr[N_NODES] = waveoff + incl;
}

// ---------------------------------------------------------------------------
// K3: scatter edges into CSR (counting sort; order within segment irrelevant)
__global__ void k_scatter(const int* __restrict__ src, const int* __restrict__ dst,
                          int* __restrict__ cursor, int* __restrict__ csr_src) {
    int e = blockIdx.x * 256 + threadIdx.x;
    if (e < E_EDGES) {
        int d = dst[e];
        int p = atomicAdd(&cursor[d], 1);
        csr_src[p] = src[e];
    }
}

// ---------------------------------------------------------------------------
// K4: first graph conv aggregate: h[n] = relu(norm[n] * sum_{s->n} norm[s]*xw[s])
// one wave per node; lanes 0..31 / 32..63 process alternating edges.
// (round-0 proven: broadcast vector loads, NOT scalarized — scalar-cache
// random loads regressed in round 2.)
__global__ void k_agg1(const int* __restrict__ rowptr, const int* __restrict__ csr_src,
                       const float* __restrict__ xw, const float* __restrict__ norm,
                       float* __restrict__ h) {
    int wid = (blockIdx.x * blockDim.x + threadIdx.x) >> 6;  // node id (wave-uniform)
    if (wid >= N_NODES) return;
    int lane = threadIdx.x & 63;
    int col = lane & 31, half = lane >> 5;
    int beg = rowptr[wid], end = rowptr[wid + 1];
    float acc = 0.0f;
    for (int p = beg + half; p < end; p += 2) {
        int s = csr_src[p];
        acc += norm[s] * xw[(size_t)s * H1 + col];
    }
    acc += __shfl_xor(acc, 32, 64);
    if (half == 0) {
        float v = norm[wid] * acc;
        h[(size_t)wid * H1 + col] = fmaxf(v, 0.0f);
    }
}

// ---------------------------------------------------------------------------
// K5: per-node small math: hm[n] = norm[n]*(h[n]@Wm); dd/ds = gate dots
__global__ void k_node_small(const float* __restrict__ h, const float* __restrict__ Wm,
                             const float* __restrict__ gw, const float* __restrict__ norm,
                             float* __restrict__ hm, float* __restrict__ dd,
                             float* __restrict__ ds) {
    int n = blockIdx.x * blockDim.x + threadIdx.x;
    if (n >= N_NODES) return;
    float hv[H1];
#pragma unroll
    for (int c = 0; c < H1; c++) hv[c] = h[(size_t)n * H1 + c];
    float nn = norm[n];
#pragma unroll
    for (int j = 0; j < H2; j++) {
        float s = 0.0f;
#pragma unroll
        for (int c = 0; c < H1; c++) s += hv[c] * Wm[c * H2 + j];
        hm[(size_t)n * H2 + j] = nn * s;
    }
    float a = 0.0f, b = 0.0f;
#pragma unroll
    for (int c = 0; c < H1; c++) {
        a += hv[c] * gw[c];        // h_dst part (first 32 of gate_w)
        b += hv[c] * gw[H1 + c];   // h_src part
    }
    dd[n] = a;
    ds[n] = b;
}

// ---------------------------------------------------------------------------
// K6 (fused): per-node edge-gated aggregation + mean + logstd + reparameterize.
// Round-0 proven loop (1 edge/iter, broadcast vector loads) with two proven
// deltas from round 2: fast exp-based tanh (identical absmax on HW) and no
// block barrier (sh row is wave-private; same-wave DS write->read is ordered).
__global__ __launch_bounds__(256) void k_agg2z(const int* __restrict__ rowptr,
                                               const int* __restrict__ csr_src,
                                               const float* __restrict__ h,
                                               const float* __restrict__ hm,
                                               const float* __restrict__ dd,
                                               const float* __restrict__ ds,
                                               const float* __restrict__ norm,
                                               const float* __restrict__ gb,
                                               const float* __restrict__ t2,
                                               const float* __restrict__ noise,
                                               float* __restrict__ z) {
    __shared__ float sh[4][H1];  // one 32-float row per wave (wave-private)
    int wid = (blockIdx.x * blockDim.x + threadIdx.x) >> 6;  // node id
    int w = (threadIdx.x >> 6) & 3;                          // wave in block
    int lane = threadIdx.x & 63;
    int col = lane & 31;
    int beg = rowptr[wid], end = rowptr[wid + 1];
    float dd_n = dd[wid];
    float norm_n = norm[wid];
    float gb0 = gb[0];
    bool isZ = lane < 32;
    bool isM = (lane >= 32) && (lane < 48);
    float acc = 0.0f;
    for (int p = beg; p < end; p++) {
        int s = csr_src[p];
        // tanh(x) = (e^{2x}-1)/(e^{2x}+1), clamped (saturates ~1 for x>9)
        float x = fminf(dd_n + ds[s] + gb0, 15.0f);
        float e2 = __expf(2.0f * x);
        float cf = __fdividef(e2 - 1.0f, e2 + 1.0f) * norm_n * norm[s] * ALPHA_C;
        size_t offv = isZ ? ((size_t)s * H1 + col) : ((size_t)s * H2 + (lane & 15));
        float v = (isZ || isM) ? (isZ ? h : hm)[offv] : 0.0f;
        acc += isZ ? (v * cf) : v;
    }
    if (isZ) sh[w][col] = acc + ALPHA_C * h[(size_t)wid * H1 + col];
    // no __syncthreads(): write by lanes<32, read by lanes 32..47 of the SAME
    // wave; DS ops from one wave complete in order (HW-verified in round 2).
    if (isM) {
        int k = lane & 15;
        float ls = 0.0f;
#pragma unroll
        for (int c = 0; c < H1; c++) ls += sh[w][c] * t2[c * H2 + k];
        size_t zi = (size_t)wid * H2 + k;
        z[zi] = noise[zi] * __expf(ls) + norm_n * acc;
    }
}

// ---------------------------------------------------------------------------
// K7: out = sigmoid(z @ z^T), 128x128 tile per block, 8x8 per thread.
// a-frag reads broadcast, b-frag 2-way (free); non-temporal coalesced stores.
__global__ __launch_bounds__(256) void k_outer(const float* __restrict__ z,
                                               float* __restrict__ out) {
    __shared__ float Zr[H2][128];
    __shared__ float Zc[H2][128];
    const int bx = blockIdx.x, by = blockIdx.y;
    const int t = threadIdx.x;
#pragma unroll
    for (int p = 0; p < 2; p++) {
        int fi = t + p * 256;
        int row = fi >> 2, q = fi & 3;
        float4 v = *(const float4*)&z[(size_t)(by * 128 + row) * H2 + q * 4];
        Zr[q * 4 + 0][row] = v.x; Zr[q * 4 + 1][row] = v.y;
        Zr[q * 4 + 2][row] = v.z; Zr[q * 4 + 3][row] = v.w;
        float4 w = *(const float4*)&z[(size_t)(bx * 128 + row) * H2 + q * 4];
        Zc[q * 4 + 0][row] = w.x; Zc[q * 4 + 1][row] = w.y;
        Zc[q * 4 + 2][row] = w.z; Zc[q * 4 + 3][row] = w.w;
    }
    __syncthreads();
    const int tx = t & 15, ty = t >> 4;
    float acc[8][8] = {};
#pragma unroll
    for (int k = 0; k < H2; k++) {
        float a[8], b[8];
        *(float4*)&a[0] = *(const float4*)&Zr[k][ty * 4];
        *(float4*)&a[4] = *(const float4*)&Zr[k][64 + ty * 4];
        *(float4*)&b[0] = *(const float4*)&Zc[k][tx * 4];
        *(float4*)&b[4] = *(const float4*)&Zc[k][64 + tx * 4];
#pragma unroll
        for (int i = 0; i < 8; i++)
#pragma unroll
            for (int j = 0; j < 8; j++) acc[i][j] += a[i] * b[j];
    }
#pragma unroll
    for (int i = 0; i < 8; i++) {
        size_t row = (size_t)by * 128 + ((i < 4) ? (ty * 4 + i) : (64 + ty * 4 + i - 4));
        f4v o0, o1;
        o0.x = 1.0f / (1.0f + __expf(-acc[i][0]));
        o0.y = 1.0f / (1.0f + __expf(-acc[i][1]));
        o0.z = 1.0f / (1.0f + __expf(-acc[i][2]));
        o0.w = 1.0f / (1.0f + __expf(-acc[i][3]));
        o1.x = 1.0f / (1.0f + __expf(-acc[i][4]));
        o1.y = 1.0f / (1.0f + __expf(-acc[i][5]));
        o1.z = 1.0f / (1.0f + __expf(-acc[i][6]));
        o1.w = 1.0f / (1.0f + __expf(-acc[i][7]));
        __builtin_nontemporal_store(o0, (f4v*)&out[row * N_NODES + bx * 128 + tx * 4]);
        __builtin_nontemporal_store(o1, (f4v*)&out[row * N_NODES + bx * 128 + 64 + tx * 4]);
    }
}

// ---------------------------------------------------------------------------
extern "C" void kernel_launch(void* const* d_in, const int* in_sizes, int n_in,
                              void* d_out, int out_size, void* d_ws, size_t ws_size,
                              hipStream_t stream) {
    const float* feat  = (const float*)d_in[0];
    const float* W0    = (const float*)d_in[1];
    const float* Wm    = (const float*)d_in[2];
    const float* gw    = (const float*)d_in[3];
    const float* gb    = (const float*)d_in[4];
    const float* t2    = (const float*)d_in[5];
    const float* noise = (const float*)d_in[6];
    const int*   src   = (const int*)d_in[7];
    const int*   dst   = (const int*)d_in[8];
    float* out = (float*)d_out;

    char* w = (char*)d_ws;
    size_t off = 0;
    auto alloc = [&](size_t bytes) {
        void* p = w + off;
        off = (off + bytes + 255) & ~(size_t)255;
        return p;
    };
    // deg and xw first + contiguous -> single zeroing memset
    int*   deg     = (int*)alloc(N_NODES * 4);
    float* xw      = (float*)alloc((size_t)N_NODES * H1 * 4);
    size_t zero_bytes = off;
    int*   rowptr  = (int*)alloc((N_NODES + 1) * 4);
    int*   cursor  = (int*)alloc(N_NODES * 4);
    int*   csr_src = (int*)alloc(E_EDGES * 4);
    float* norm    = (float*)alloc(N_NODES * 4);
    float* h       = (float*)alloc((size_t)N_NODES * H1 * 4);
    float* hm      = (float*)alloc((size_t)N_NODES * H2 * 4);
    float* dd      = (float*)alloc(N_NODES * 4);
    float* ds      = (float*)alloc(N_NODES * 4);
    float* z       = (float*)alloc((size_t)N_NODES * H2 * 4);

    (void)hipMemsetAsync(deg, 0, zero_bytes, stream);

    // GEMM blocks [0,1024) + degree blocks [1024,2048) run concurrently
    k_gemm_deg<<<2048, 256, 0, stream>>>(feat, W0, xw, dst, deg);
    k_scan<<<1, 1024, 0, stream>>>(deg, rowptr, cursor, norm);
    k_scatter<<<E_EDGES / 256, 256, 0, stream>>>(src, dst, cursor, csr_src);
    k_agg1<<<N_NODES / 4, 256, 0, stream>>>(rowptr, csr_src, xw, norm, h);
    k_node_small<<<N_NODES / 256, 256, 0, stream>>>(h, Wm, gw, norm, hm, dd, ds);
    k_agg2z<<<N_NODES / 4, 256, 0, stream>>>(rowptr, csr_src, h, hm, dd, ds, norm,
                                             gb, t2, noise, z);
    k_outer<<<dim3(N_NODES / 128, N_NODES / 128), 256, 0, stream>>>(z, out);
}

// Round 4
// 429.746 us; speedup vs baseline: 1.1029x; 1.0308x over previous
//
#include <hip/hip_runtime.h>
#include <math.h>

#define N_NODES 8192
#define F_DIM   2048
#define E_EDGES 262144
#define H1      32
#define H2      16
#define ALPHA_C 0.9f

typedef float f4v __attribute__((ext_vector_type(4)));

// ---------------------------------------------------------------------------
// K1 (fused): blocks [0,1024) = GEMM xw = feat @ W0; blocks [1024,2048) =
// in-degree histogram. Independent work overlapped (proven round 3).
// GEMM: BM=128, BN=32, BK=32, 256 thr, TM=4, TN=4, split-K=16.
__global__ __launch_bounds__(256) void k_gemm_deg(const float* __restrict__ feat,
                                                  const float* __restrict__ W0,
                                                  float* __restrict__ xw,
                                                  const int* __restrict__ dst,
                                                  int* __restrict__ deg) {
    __shared__ float As[128][36];
    __shared__ float Bt[32][36];
    const int b = blockIdx.x;
    if (b >= 1024) {
        // ---- degree histogram path ----
        int e = (b - 1024) * 256 + threadIdx.x;
        if (e < E_EDGES) atomicAdd(&deg[dst[e]], 1);
        return;
    }
    // ---- GEMM path ----
    const int r0 = (b >> 4) * 128;        // 64 row-blocks
    const int kbase = (b & 15) * 128;     // 16 K-slices
    const int t = threadIdx.x;
    const int ct = t & 7;    // 8 col-threads  (cols ct + 8j)
    const int rt = t >> 3;   // 32 row-threads (rows rt + 32m)
    float acc[4][4] = {};
    for (int kb = 0; kb < 128; kb += 32) {
        const int koff = kbase + kb;
        __syncthreads();
#pragma unroll
        for (int p = 0; p < 4; p++) {
            int f = t + p * 256;
            int row = f >> 3, q = f & 7;
            float4 v = *(const float4*)&feat[(size_t)(r0 + row) * F_DIM + koff + q * 4];
            *(float4*)&As[row][q * 4] = v;
        }
        {
            int k = t >> 3, q = t & 7;
            float4 v = *(const float4*)&W0[(size_t)(koff + k) * H1 + q * 4];
            Bt[q * 4 + 0][k] = v.x; Bt[q * 4 + 1][k] = v.y;
            Bt[q * 4 + 2][k] = v.z; Bt[q * 4 + 3][k] = v.w;
        }
        __syncthreads();
#pragma unroll
        for (int k4 = 0; k4 < 8; k4++) {
            float4 a[4], bb[4];
#pragma unroll
            for (int m = 0; m < 4; m++) a[m] = *(const float4*)&As[rt + 32 * m][k4 * 4];
#pragma unroll
            for (int j = 0; j < 4; j++) bb[j] = *(const float4*)&Bt[ct + 8 * j][k4 * 4];
#pragma unroll
            for (int m = 0; m < 4; m++)
#pragma unroll
                for (int j = 0; j < 4; j++)
                    acc[m][j] += a[m].x * bb[j].x + a[m].y * bb[j].y +
                                 a[m].z * bb[j].z + a[m].w * bb[j].w;
        }
    }
#pragma unroll
    for (int m = 0; m < 4; m++)
#pragma unroll
        for (int j = 0; j < 4; j++)
            atomicAdd(&xw[(size_t)(r0 + rt + 32 * m) * H1 + ct + 8 * j], acc[m][j]);
}

// ---------------------------------------------------------------------------
// K2: exclusive prefix scan of deg -> rowptr, cursor; norm = rsqrt(max(deg,1))
// shuffle-based scan (proven rounds 2-3).
__global__ void k_scan(const int* __restrict__ deg, int* __restrict__ rowptr,
                       int* __restrict__ cursor, float* __restrict__ norm) {
    __shared__ int wsum[16];
    int t = threadIdx.x;          // 0..1023
    int base = t * 8;
    int local[8];
    int s = 0;
#pragma unroll
    for (int i = 0; i < 8; i++) { local[i] = s; s += deg[base + i]; }
    int lane = t & 63, wv = t >> 6;
    int incl = s;
#pragma unroll
    for (int off = 1; off < 64; off <<= 1) {
        int u = __shfl_up(incl, off);
        if (lane >= off) incl += u;
    }
    if (lane == 63) wsum[wv] = incl;
    __syncthreads();
    if (t < 16) {
        int x = wsum[t];
#pragma unroll
        for (int off = 1; off < 16; off <<= 1) {
            int u = __shfl_up(x, off);
            if (t >= off) x += u;
        }
        wsum[t] = x;   // inclusive scan of the 16 wave sums
    }
    __syncthreads();
    int waveoff = (wv == 0) ? 0 : wsum[wv - 1];
    int excl = waveoff + incl - s;   // exclusive offset for this thread's 8 elems
#pragma unroll
    for (int i = 0; i < 8; i++) {
        int r = excl + local[i];
        rowptr[base + i] = r;
        cursor[base + i] = r;
        int d = ((i == 7) ? s : local[i + 1]) - local[i];
        norm[base + i] = rsqrtf((float)(d > 0 ? d : 1));
    }
    if (t == 1023) rowptr[N_NODES] = waveoff + incl;
}

// ---------------------------------------------------------------------------
// K3: scatter edges into CSR (counting sort; order within segment irrelevant)
__global__ void k_scatter(const int* __restrict__ src, const int* __restrict__ dst,
                          int* __restrict__ cursor, int* __restrict__ csr_src) {
    int e = blockIdx.x * 256 + threadIdx.x;
    if (e < E_EDGES) {
        int d = dst[e];
        int p = atomicAdd(&cursor[d], 1);
        csr_src[p] = src[e];
    }
}

// ---------------------------------------------------------------------------
// K4 (fused): first graph conv aggregate + gate dots.
// h[n] = relu(norm[n] * sum_{s->n} norm[s]*xw[s]); edge loop = round-0 proven
// (broadcast vector loads, halves on alternating edges). After the cross-half
// reduce ALL 64 lanes hold the column total, so dd/ds fold in as two 32-lane
// shuffle reductions on registers (k_node_small deleted; 1MB less h re-read).
__global__ __launch_bounds__(256) void k_agg1(const int* __restrict__ rowptr,
                                              const int* __restrict__ csr_src,
                                              const float* __restrict__ xw,
                                              const float* __restrict__ norm,
                                              const float* __restrict__ gw,
                                              float* __restrict__ h,
                                              float* __restrict__ dd,
                                              float* __restrict__ ds) {
    int wid = (blockIdx.x * blockDim.x + threadIdx.x) >> 6;  // node id (wave-uniform)
    int lane = threadIdx.x & 63;
    int col = lane & 31, half = lane >> 5;
    int beg = rowptr[wid], end = rowptr[wid + 1];
    float acc = 0.0f;
    for (int p = beg + half; p < end; p += 2) {
        int s = csr_src[p];
        acc += norm[s] * xw[(size_t)s * H1 + col];
    }
    acc += __shfl_xor(acc, 32, 64);          // both halves hold col total
    float hv = fmaxf(norm[wid] * acc, 0.0f); // valid on all 64 lanes
    if (half == 0) h[(size_t)wid * H1 + col] = hv;
    // dd[n] = h[n]@gw[0:32], ds[n] = h[n]@gw[32:64]; reduce within each
    // 32-lane half (xor offsets stay inside the half; both halves identical)
    float c0 = hv * gw[col];
    float c1 = hv * gw[H1 + col];
#pragma unroll
    for (int off = 1; off < 32; off <<= 1) {
        c0 += __shfl_xor(c0, off);
        c1 += __shfl_xor(c1, off);
    }
    if (lane == 0) { dd[wid] = c0; ds[wid] = c1; }
}

// ---------------------------------------------------------------------------
// K5 (fused): edge-gated aggregation + mean + logstd + reparameterize.
// KEY: mean = norm_n * (sum_s norm_s*h[s]) @ Wm  (linearity) -> the mean
// reuses the SAME h[s][col] gather as z_auto. No hm gather/buffer at all;
// halves process alternating edges (16 iters/wave vs 32); all lanes busy.
// Epilogue matvecs (32->16, x2) on lanes 0..15 via wave-private LDS rows
// (same-wave DS write->read ordering, HW-proven rounds 2-3; no barrier).
__global__ __launch_bounds__(256) void k_agg2z(const int* __restrict__ rowptr,
                                               const int* __restrict__ csr_src,
                                               const float* __restrict__ h,
                                               const float* __restrict__ dd,
                                               const float* __restrict__ ds,
                                               const float* __restrict__ norm,
                                               const float* __restrict__ gb,
                                               const float* __restrict__ t2,
                                               const float* __restrict__ Wm,
                                               const float* __restrict__ noise,
                                               float* __restrict__ z) {
    __shared__ float shT[4][H1];  // t-vector row per wave (wave-private)
    __shared__ float shH[4][H1];  // norm_n * sum norm_s h[s] row per wave
    int wid = (blockIdx.x * blockDim.x + threadIdx.x) >> 6;  // node id
    int w = (threadIdx.x >> 6) & 3;                          // wave in block
    int lane = threadIdx.x & 63;
    int col = lane & 31, half = lane >> 5;
    int beg = rowptr[wid], end = rowptr[wid + 1];
    float dd_n = dd[wid];
    float norm_n = norm[wid];
    float gb0 = gb[0];
    float accz = 0.0f, acch = 0.0f;
    for (int p = beg + half; p < end; p += 2) {
        int s = csr_src[p];
        float ns = norm[s];
        // tanh(x) = (e^{2x}-1)/(e^{2x}+1), clamped (proven identical absmax)
        float x = fminf(dd_n + ds[s] + gb0, 15.0f);
        float e2 = __expf(2.0f * x);
        float th = __fdividef(e2 - 1.0f, e2 + 1.0f);
        float hv = h[(size_t)s * H1 + col];    // single gather feeds BOTH sums
        accz += th * ns * hv;
        acch += ns * hv;
    }
    accz += __shfl_xor(accz, 32);
    acch += __shfl_xor(acch, 32);
    if (half == 0) {
        // t[c] = z_auto + alpha*h[n];  z_auto = norm_n*alpha*accz
        shT[w][col] = accz * (norm_n * ALPHA_C) + ALPHA_C * h[(size_t)wid * H1 + col];
        shH[w][col] = acch * norm_n;           // mean = shH @ Wm
    }
    // no __syncthreads(): same-wave DS write->read is ordered (HW-proven)
    if (lane < 16) {
        int k = lane;
        float ls = 0.0f, mn = 0.0f;
#pragma unroll
        for (int c = 0; c < H1; c++) {
            ls += shT[w][c] * t2[c * H2 + k];
            mn += shH[w][c] * Wm[c * H2 + k];
        }
        size_t zi = (size_t)wid * H2 + k;
        z[zi] = noise[zi] * __expf(ls) + mn;
    }
}

// ---------------------------------------------------------------------------
// K6: out = sigmoid(z @ z^T), 128x128 tile per block, 8x8 per thread.
__global__ __launch_bounds__(256) void k_outer(const float* __restrict__ z,
                                               float* __restrict__ out) {
    __shared__ float Zr[H2][128];
    __shared__ float Zc[H2][128];
    const int bx = blockIdx.x, by = blockIdx.y;
    const int t = threadIdx.x;
#pragma unroll
    for (int p = 0; p < 2; p++) {
        int fi = t + p * 256;
        int row = fi >> 2, q = fi & 3;
        float4 v = *(const float4*)&z[(size_t)(by * 128 + row) * H2 + q * 4];
        Zr[q * 4 + 0][row] = v.x; Zr[q * 4 + 1][row] = v.y;
        Zr[q * 4 + 2][row] = v.z; Zr[q * 4 + 3][row] = v.w;
        float4 w = *(const float4*)&z[(size_t)(bx * 128 + row) * H2 + q * 4];
        Zc[q * 4 + 0][row] = w.x; Zc[q * 4 + 1][row] = w.y;
        Zc[q * 4 + 2][row] = w.z; Zc[q * 4 + 3][row] = w.w;
    }
    __syncthreads();
    const int tx = t & 15, ty = t >> 4;
    float acc[8][8] = {};
#pragma unroll
    for (int k = 0; k < H2; k++) {
        float a[8], b[8];
        *(float4*)&a[0] = *(const float4*)&Zr[k][ty * 4];
        *(float4*)&a[4] = *(const float4*)&Zr[k][64 + ty * 4];
        *(float4*)&b[0] = *(const float4*)&Zc[k][tx * 4];
        *(float4*)&b[4] = *(const float4*)&Zc[k][64 + tx * 4];
#pragma unroll
        for (int i = 0; i < 8; i++)
#pragma unroll
            for (int j = 0; j < 8; j++) acc[i][j] += a[i] * b[j];
    }
#pragma unroll
    for (int i = 0; i < 8; i++) {
        size_t row = (size_t)by * 128 + ((i < 4) ? (ty * 4 + i) : (64 + ty * 4 + i - 4));
        f4v o0, o1;
        o0.x = 1.0f / (1.0f + __expf(-acc[i][0]));
        o0.y = 1.0f / (1.0f + __expf(-acc[i][1]));
        o0.z = 1.0f / (1.0f + __expf(-acc[i][2]));
        o0.w = 1.0f / (1.0f + __expf(-acc[i][3]));
        o1.x = 1.0f / (1.0f + __expf(-acc[i][4]));
        o1.y = 1.0f / (1.0f + __expf(-acc[i][5]));
        o1.z = 1.0f / (1.0f + __expf(-acc[i][6]));
        o1.w = 1.0f / (1.0f + __expf(-acc[i][7]));
        __builtin_nontemporal_store(o0, (f4v*)&out[row * N_NODES + bx * 128 + tx * 4]);
        __builtin_nontemporal_store(o1, (f4v*)&out[row * N_NODES + bx * 128 + 64 + tx * 4]);
    }
}

// ---------------------------------------------------------------------------
extern "C" void kernel_launch(void* const* d_in, const int* in_sizes, int n_in,
                              void* d_out, int out_size, void* d_ws, size_t ws_size,
                              hipStream_t stream) {
    const float* feat  = (const float*)d_in[0];
    const float* W0    = (const float*)d_in[1];
    const float* Wm    = (const float*)d_in[2];
    const float* gw    = (const float*)d_in[3];
    const float* gb    = (const float*)d_in[4];
    const float* t2    = (const float*)d_in[5];
    const float* noise = (const float*)d_in[6];
    const int*   src   = (const int*)d_in[7];
    const int*   dst   = (const int*)d_in[8];
    float* out = (float*)d_out;

    char* w = (char*)d_ws;
    size_t off = 0;
    auto alloc = [&](size_t bytes) {
        void* p = w + off;
        off = (off + bytes + 255) & ~(size_t)255;
        return p;
    };
    // deg and xw first + contiguous -> single zeroing memset
    int*   deg     = (int*)alloc(N_NODES * 4);
    float* xw      = (float*)alloc((size_t)N_NODES * H1 * 4);
    size_t zero_bytes = off;
    int*   rowptr  = (int*)alloc((N_NODES + 1) * 4);
    int*   cursor  = (int*)alloc(N_NODES * 4);
    int*   csr_src = (int*)alloc(E_EDGES * 4);
    float* norm    = (float*)alloc(N_NODES * 4);
    float* h       = (float*)alloc((size_t)N_NODES * H1 * 4);
    float* dd      = (float*)alloc(N_NODES * 4);
    float* ds      = (float*)alloc(N_NODES * 4);
    float* z       = (float*)alloc((size_t)N_NODES * H2 * 4);

    (void)hipMemsetAsync(deg, 0, zero_bytes, stream);

    // GEMM blocks [0,1024) + degree blocks [1024,2048) run concurrently
    k_gemm_deg<<<2048, 256, 0, stream>>>(feat, W0, xw, dst, deg);
    k_scan<<<1, 1024, 0, stream>>>(deg, rowptr, cursor, norm);
    k_scatter<<<E_EDGES / 256, 256, 0, stream>>>(src, dst, cursor, csr_src);
    k_agg1<<<N_NODES / 4, 256, 0, stream>>>(rowptr, csr_src, xw, norm, gw, h, dd, ds);
    k_agg2z<<<N_NODES / 4, 256, 0, stream>>>(rowptr, csr_src, h, dd, ds, norm,
                                             gb, t2, Wm, noise, z);
    k_outer<<<dim3(N_NODES / 128, N_NODES / 128), 256, 0, stream>>>(z, out);
}